// Round 2
// baseline (375.895 us; speedup 1.0000x reference)
//
#include <hip/hip_runtime.h>
#include <hip/hip_bf16.h>
#include <math.h>

#define BB 4
#define DD 60
#define SS 512
#define FF 158
#define CC 64
#define HH 128
#define FC 222      // F + C
#define G3 384      // 3H
#define NN 2048     // B*S
#define BDN 240     // B*D

typedef _Float16 f16x8 __attribute__((ext_vector_type(8)));
typedef float f32x4 __attribute__((ext_vector_type(4)));

__device__ __forceinline__ float sigmoidf_(float x){ return 1.0f/(1.0f+__expf(-x)); }
// tanh(x) = 1 - 2/(e^{2x}+1): 5 VALU ops, saturates correctly at +/-inf
__device__ __forceinline__ float tanh_fast_(float x){
    float e = __expf(2.0f*x);
    return 1.0f - 2.0f/(e + 1.0f);
}

// ---- prep: wf16 (384x224) xproj, wqkv (192x160) qkv, whh16 (384x128) gru -------------
__global__ void prep_kernel(const float* __restrict__ w_ih,
                            const float* __restrict__ wq, const float* __restrict__ wk,
                            const float* __restrict__ wv, const float* __restrict__ w_hh,
                            _Float16* __restrict__ wf16, _Float16* __restrict__ wqkv,
                            _Float16* __restrict__ whh16){
    int idx = blockIdx.x*256 + threadIdx.x;
    if (idx < 384*224){
        int n = idx / 224, k = idx % 224;
        wf16[idx] = (k < FC) ? (_Float16)w_ih[n*FC + k] : (_Float16)0.0f;
    } else if (idx < 384*224 + 192*160){
        int i2 = idx - 384*224;
        int n = i2 / 160, k = i2 % 160;
        float v = 0.0f;
        if (k < FF){
            if (n < 64)       v = wq[k*CC + n];
            else if (n < 128) v = wk[k*CC + (n-64)];
            else              v = wv[k*CC + (n-128)];
        }
        wqkv[i2] = (_Float16)v;
    } else {
        int i3 = idx - (384*224 + 192*160);
        if (i3 < 384*128)
            whh16[i3] = (_Float16)w_hh[i3];
    }
}

// ---------------- QKV via f16 MFMA: 64 rows/block, 256 thr (4 waves) ------------------
__global__ __launch_bounds__(256) void qkv_kernel(const float* __restrict__ x,
                           const _Float16* __restrict__ wqkv,
                           const float* __restrict__ bq, const float* __restrict__ bk,
                           const float* __restrict__ bv,
                           _Float16* __restrict__ Qh, _Float16* __restrict__ Kh,
                           float* __restrict__ V){
    __shared__ _Float16 xa[5][64][40];   // fragment layout, 25.6 KB
    int tid  = threadIdx.x;
    int lane = tid & 63, wv = tid >> 6;
    int col  = lane & 15, quad = lane >> 4;
    int row0 = blockIdx.x * 64;

    f16x8 bfr[3][5];
    #pragma unroll
    for (int nt = 0; nt < 3; ++nt){
        int n = wv*48 + nt*16 + col;
        #pragma unroll
        for (int kq = 0; kq < 5; ++kq)
            bfr[nt][kq] = *(const f16x8*)&wqkv[n*160 + kq*32 + quad*8];
    }

    for (int i = tid; i < 64*160; i += 256){
        int r = i / 160, k = i % 160;
        float v = (k < FF) ? x[(size_t)(row0 + r)*FF + k] : 0.0f;
        xa[k >> 5][r][k & 31] = (_Float16)v;
    }
    __syncthreads();

    float bias[3];
    #pragma unroll
    for (int nt = 0; nt < 3; ++nt){
        int n = wv*48 + nt*16 + col;
        bias[nt] = (n < 64) ? bq[n] : (n < 128 ? bk[n-64] : bv[n-128]);
    }

    #pragma unroll 1
    for (int mt = 0; mt < 4; ++mt){
        f16x8 a[5];
        #pragma unroll
        for (int kq = 0; kq < 5; ++kq)
            a[kq] = *(const f16x8*)&xa[kq][mt*16 + col][quad*8];
        #pragma unroll
        for (int nt = 0; nt < 3; ++nt){
            f32x4 c = {0.0f, 0.0f, 0.0f, 0.0f};
            #pragma unroll
            for (int kq = 0; kq < 5; ++kq)
                c = __builtin_amdgcn_mfma_f32_16x16x32_f16(a[kq], bfr[nt][kq], c, 0, 0, 0);
            int n = wv*48 + nt*16 + col;
            #pragma unroll
            for (int reg = 0; reg < 4; ++reg){
                int row = row0 + mt*16 + quad*4 + reg;
                float val = c[reg] + bias[nt];
                if (n < 64)       Qh[(size_t)row*CC + n]       = (_Float16)val;
                else if (n < 128) Kh[(size_t)row*CC + (n-64)]  = (_Float16)val;
                else              V [(size_t)row*CC + (n-128)] = val;
            }
        }
    }
}

// ---------------- attention + fused market: one block per bd --------------------------
__global__ __launch_bounds__(512) void attn_kernel(const _Float16* __restrict__ Qh,
                                                   const _Float16* __restrict__ Kh,
                                                   const int* __restrict__ mask,
                                                   const float* __restrict__ V,
                                                   float* __restrict__ market){
    __shared__ _Float16 kf[2][512][32];   // 64 KB
    __shared__ float w_sh[512];
    __shared__ float mk_lds[512];

    int tid  = threadIdx.x;
    int bd   = blockIdx.x;
    int lane = tid & 63, wv = tid >> 6;
    int col  = lane & 15, quad = lane >> 4;

    const _Float16* qb = Qh + (size_t)(bd*SS)*CC;
    const _Float16* kb = Kh + (size_t)(bd*SS)*CC;

    {
        int t = tid;
        w_sh[t] = 0.0f;
        mk_lds[t] = (mask[bd*SS + t] != 0) ? 1.0f : 0.0f;
    }
    for (int i = tid; i < 4096; i += 512){
        int t = i >> 3, ch = i & 7;
        *(f16x8*)&kf[ch >> 2][t][(ch & 3)*8] = *(const f16x8*)&kb[t*CC + ch*8];
    }

    f16x8 a0[4], a1[4];
    #pragma unroll
    for (int af = 0; af < 4; ++af){
        int row = wv*64 + af*16 + col;
        a0[af] = *(const f16x8*)&qb[row*CC + quad*8];
        a1[af] = *(const f16x8*)&qb[row*CC + 32 + quad*8];
    }
    __syncthreads();

    // ---- pass 0: row sums l ----
    float lacc[4][4] = {{0,0,0,0},{0,0,0,0},{0,0,0,0},{0,0,0,0}};
    #pragma unroll 2
    for (int kt = 0; kt < 32; ++kt){
        f16x8 b0 = *(const f16x8*)&kf[0][kt*16 + col][quad*8];
        f16x8 b1 = *(const f16x8*)&kf[1][kt*16 + col][quad*8];
        float mkv = mk_lds[kt*16 + col];
        #pragma unroll
        for (int af = 0; af < 4; ++af){
            f32x4 c = {0.0f, 0.0f, 0.0f, 0.0f};
            c = __builtin_amdgcn_mfma_f32_16x16x32_f16(a0[af], b0, c, 0, 0, 0);
            c = __builtin_amdgcn_mfma_f32_16x16x32_f16(a1[af], b1, c, 0, 0, 0);
            #pragma unroll
            for (int reg = 0; reg < 4; ++reg)
                lacc[af][reg] += __expf(c[reg]*0.125f) * mkv;
        }
    }
    float crv[4][4];
    #pragma unroll
    for (int af = 0; af < 4; ++af){
        #pragma unroll
        for (int reg = 0; reg < 4; ++reg){
            float l = lacc[af][reg];
            l += __shfl_xor(l, 1, 64);
            l += __shfl_xor(l, 2, 64);
            l += __shfl_xor(l, 4, 64);
            l += __shfl_xor(l, 8, 64);
            int row = wv*64 + af*16 + quad*4 + reg;
            crv[af][reg] = mk_lds[row] / l;
        }
    }

    // ---- pass 1: accumulate W columns ----
    #pragma unroll 2
    for (int kt = 0; kt < 32; ++kt){
        f16x8 b0 = *(const f16x8*)&kf[0][kt*16 + col][quad*8];
        f16x8 b1 = *(const f16x8*)&kf[1][kt*16 + col][quad*8];
        float s = 0.0f;
        #pragma unroll
        for (int af = 0; af < 4; ++af){
            f32x4 c = {0.0f, 0.0f, 0.0f, 0.0f};
            c = __builtin_amdgcn_mfma_f32_16x16x32_f16(a0[af], b0, c, 0, 0, 0);
            c = __builtin_amdgcn_mfma_f32_16x16x32_f16(a1[af], b1, c, 0, 0, 0);
            #pragma unroll
            for (int reg = 0; reg < 4; ++reg)
                s = fmaf(__expf(c[reg]*0.125f), crv[af][reg], s);
        }
        s += __shfl_xor(s, 16, 64);
        s += __shfl_xor(s, 32, 64);
        if (quad == 0)
            atomicAdd(&w_sh[kt*16 + col], s);
    }
    __syncthreads();   // w_sh final; kf reads complete -> reuse kf as scratch

    // ---- fused market ----
    float* msum = (float*)kf;
    {
        int c = tid & 63, grp = tid >> 6;
        const float* vb = V + (size_t)(bd*SS)*CC;
        float acc = 0.0f;
        int t0 = grp*64;
        #pragma unroll 4
        for (int t = t0; t < t0 + 64; ++t)
            acc = fmaf(w_sh[t]*mk_lds[t], vb[(size_t)t*CC + c], acc);
        msum[grp*64 + c] = acc;
    }
    __syncthreads();
    if (tid < 64){
        float s = 0.0f;
        #pragma unroll
        for (int g = 0; g < 8; ++g) s += msum[g*64 + tid];
        float cnt = 0.0f;
        #pragma unroll
        for (int j = 0; j < 8; ++j) cnt += mk_lds[tid + 64*j];
        #pragma unroll
        for (int o = 1; o < 64; o <<= 1) cnt += __shfl_xor(cnt, o, 64);
        market[bd*CC + tid] = s / fmaxf(cnt, 1.0f);
    }
}

// ---------------- fused LN + x_proj f16 MFMA GEMM -------------------------------------
__global__ __launch_bounds__(512, 2) void xproj_kernel(const float* __restrict__ x,
                             const float* __restrict__ market,
                             const float* __restrict__ ln_g, const float* __restrict__ ln_b,
                             const _Float16* __restrict__ wf16, const float* __restrict__ b_ih,
                             _Float16* __restrict__ XP){
    __shared__ _Float16 aug[7][64][32];   // 28 KB
    int tid  = threadIdx.x;
    int lane = tid & 63, wv = tid >> 6;
    int col  = lane & 15, quad = lane >> 4;
    int row0 = blockIdx.x * 64;

    f16x8 bfr[3][7];
    #pragma unroll
    for (int nt = 0; nt < 3; ++nt){
        int n = wv*48 + nt*16 + col;
        #pragma unroll
        for (int kq = 0; kq < 7; ++kq)
            bfr[nt][kq] = *(const f16x8*)&wf16[n*224 + kq*32 + quad*8];
    }

    {
        int wrow = wv*8 + (lane >> 3);
        int g    = lane & 7;
        int row  = row0 + wrow;
        int d = row / NN, n = row % NN;
        int b = n >> 9, s = n & 511;
        const float* xr = &x[((size_t)((b*DD + d)*SS) + s)*FF];
        const float* mr = &market[(b*DD + d)*CC];
        float v[28];
        float sum = 0.0f, sq = 0.0f;
        #pragma unroll
        for (int j = 0; j < 28; ++j){
            int f = g + 8*j;
            float vv = 0.0f;
            if (f < FF) vv = xr[f];
            else if (f < FC) vv = mr[f - FF];
            v[j] = vv;
            sum += vv; sq += vv*vv;
        }
        sum += __shfl_xor(sum,1,64); sq += __shfl_xor(sq,1,64);
        sum += __shfl_xor(sum,2,64); sq += __shfl_xor(sq,2,64);
        sum += __shfl_xor(sum,4,64); sq += __shfl_xor(sq,4,64);
        float mu   = sum * (1.0f/222.0f);
        float var  = sq * (1.0f/222.0f) - mu*mu;
        float rstd = rsqrtf(var + 1e-5f);
        #pragma unroll
        for (int j = 0; j < 28; ++j){
            int f = g + 8*j;
            float val = (f < FC) ? ((v[j]-mu)*rstd*ln_g[f] + ln_b[f]) : 0.0f;
            aug[f>>5][wrow][f&31] = (_Float16)val;
        }
    }
    __syncthreads();

    float bias[3];
    #pragma unroll
    for (int nt = 0; nt < 3; ++nt) bias[nt] = b_ih[wv*48 + nt*16 + col];
    #pragma unroll 1
    for (int mt = 0; mt < 4; ++mt){
        f16x8 a[7];
        #pragma unroll
        for (int kq = 0; kq < 7; ++kq)
            a[kq] = *(const f16x8*)&aug[kq][mt*16 + col][quad*8];
        #pragma unroll
        for (int nt = 0; nt < 3; ++nt){
            f32x4 c = {0.0f, 0.0f, 0.0f, 0.0f};
            #pragma unroll
            for (int kq = 0; kq < 7; ++kq)
                c = __builtin_amdgcn_mfma_f32_16x16x32_f16(a[kq], bfr[nt][kq], c, 0, 0, 0);
            int nn = wv*48 + nt*16 + col;
            #pragma unroll
            for (int reg = 0; reg < 4; ++reg){
                int m = quad*4 + reg;
                XP[(size_t)(row0 + mt*16 + m)*G3 + nn] = (_Float16)(c[reg] + bias[nt]);
            }
        }
    }
}

// ---------------- persistent GRU v3: 16 seqs/block, no-vmcnt-drain barrier ------------
// 128 blocks x 512 thr (8 waves), 16 seqs/block, MFMA M=16 fully used.
// KEY FIX vs v2: in-loop barrier is raw `s_waitcnt lgkmcnt(0); s_barrier` (asm, memory
// clobber) instead of __syncthreads(), whose implicit vmcnt(0) drained the per-step XP
// prefetch loads and exposed ~900 cyc HBM latency EVERY step. The LDS h-handoff only
// needs lgkmcnt drained; the compiler's auto counted-vmcnt before each xb consumption
// correctly covers the depth-2 global prefetch, which now stays in flight across the
// barrier (T3/T4 pattern).
// hfrag padded [16][40] (80B rows, 16B aligned): b128 read conflict 4-way -> 2-way(free).
#define XLOAD(dst, base_) do{                                                   \
    _Pragma("unroll") for (int rg_ = 0; rg_ < 4; ++rg_)                         \
    _Pragma("unroll") for (int g_ = 0; g_ < 3; ++g_)                            \
        dst[rg_][g_] = (base_)[rg_*G3 + g_*HH];                                 \
}while(0)

#define BARRIER_NODRAIN() asm volatile("s_waitcnt lgkmcnt(0)\ns_barrier" ::: "memory")

#define GRU_STEP(PRD, PWR, XC, XPF, DOPF) do{                                   \
    if (DOPF) { XLOAD(XPF, xp_d + 2*DSTR); }                                    \
    f16x8 a_[4];                                                                \
    _Pragma("unroll") for (int kq = 0; kq < 4; ++kq)                            \
        a_[kq] = *(const f16x8*)&hfrag[PRD][kq][col][quad*8];                   \
    f32x4 c0 = {0,0,0,0}, c1 = {0,0,0,0}, c2 = {0,0,0,0};                       \
    _Pragma("unroll") for (int kq = 0; kq < 4; ++kq)                            \
        c0 = __builtin_amdgcn_mfma_f32_16x16x32_f16(a_[kq], bfr[0][kq], c0, 0,0,0); \
    _Pragma("unroll") for (int kq = 0; kq < 4; ++kq)                            \
        c1 = __builtin_amdgcn_mfma_f32_16x16x32_f16(a_[kq], bfr[1][kq], c1, 0,0,0); \
    _Pragma("unroll") for (int kq = 0; kq < 4; ++kq)                            \
        c2 = __builtin_amdgcn_mfma_f32_16x16x32_f16(a_[kq], bfr[2][kq], c2, 0,0,0); \
    _Pragma("unroll") for (int rg = 0; rg < 4; ++rg){                           \
        float r_ = sigmoidf_((float)XC[rg][0] + c0[rg] + bh0);                  \
        float z_ = sigmoidf_((float)XC[rg][1] + c1[rg] + bh1);                  \
        float n_ = tanh_fast_((float)XC[rg][2] + r_*(c2[rg] + bh2));            \
        float h_ = n_ + z_*(hcur[rg] - n_);                                     \
        hcur[rg] = h_;                                                          \
        hfrag[PWR][w >> 1][quad*4 + rg][(w & 1)*16 + col] = (_Float16)h_;       \
    }                                                                           \
    xp_d += DSTR;                                                               \
    BARRIER_NODRAIN();                                                          \
}while(0)

__global__ __launch_bounds__(512) void gru_kernel(const _Float16* __restrict__ XP,
                                                  const _Float16* __restrict__ whh16,
                                                  const float* __restrict__ b_hh,
                                                  const float* __restrict__ w1, const float* __restrict__ b1,
                                                  const float* __restrict__ w2, const float* __restrict__ b2,
                                                  float* __restrict__ out){
    __shared__ _Float16 hfrag[2][4][16][40];  // 10 KB, MFMA-A fragment layout, dbuf, padded
    __shared__ float h_sh[16][132];           // final h for head (padded)

    const int tid  = threadIdx.x;
    const int lane = tid & 63, w = tid >> 6;      // 8 waves
    const int col  = lane & 15, quad = lane >> 4;
    const int row0 = blockIdx.x * 16;             // 16 seqs/block

    // zero h buffer 0 (h0 = 0)
    for (int i = tid; i < 2*4*16*40; i += 512)
        ((_Float16*)hfrag)[i] = (_Float16)0.0f;

    // W_hh B-fragments: n = g*128 + w*16 + col, k = kq*32 + quad*8 + j
    f16x8 bfr[3][4];
    #pragma unroll
    for (int g = 0; g < 3; ++g){
        #pragma unroll
        for (int kq = 0; kq < 4; ++kq)
            bfr[g][kq] = *(const f16x8*)&whh16[(size_t)(g*HH + w*16 + col)*HH + kq*32 + quad*8];
    }

    const float bh0 = b_hh[0*HH + w*16 + col];
    const float bh1 = b_hh[1*HH + w*16 + col];
    const float bh2 = b_hh[2*HH + w*16 + col];

    const size_t DSTR = (size_t)NN * G3;
    // thread's 12 XP values per step: seq = row0+quad*4+rg, col g*128 + w*16 + col
    const _Float16* xp_d = XP + (size_t)(row0 + quad*4)*G3 + (w*16 + col);

    _Float16 xA[4][3], xB[4][3], xC[4][3];
    XLOAD(xA, xp_d);            // d = 0
    XLOAD(xB, xp_d + DSTR);     // d = 1

    float hcur[4] = {0.0f, 0.0f, 0.0f, 0.0f};
    __syncthreads();            // once: hfrag zero-init visible (drain here is fine)

    #pragma unroll 1
    for (int ch = 0; ch < 10; ++ch){
        const int pf = (ch < 9);          // last chunk: d+2 would be >= 60
        GRU_STEP(0, 1, xA, xC, 1);
        GRU_STEP(1, 0, xB, xA, 1);
        GRU_STEP(0, 1, xC, xB, 1);
        GRU_STEP(1, 0, xA, xC, 1);
        GRU_STEP(0, 1, xB, xA, pf);
        GRU_STEP(1, 0, xC, xB, pf);
    }

    #pragma unroll
    for (int rg = 0; rg < 4; ++rg)
        h_sh[quad*4 + rg][w*16 + col] = hcur[rg];
    __syncthreads();

    // ---- output head: 512 thr -> 8 rows in parallel, 2 passes ----
    {
        int c2 = tid & 63;
        int rb = tid >> 6;
        #pragma unroll
        for (int rr = 0; rr < 2; ++rr){
            int r = rb + rr*8;
            float acc = 0.0f;
            #pragma unroll 8
            for (int k = 0; k < 128; ++k)
                acc = fmaf(h_sh[r][k], w1[k*64 + c2], acc);
            float hid = fmaxf(acc + b1[c2], 0.0f);
            float o = hid * w2[c2];
            #pragma unroll
            for (int off = 1; off < 64; off <<= 1) o += __shfl_xor(o, off, 64);
            if (c2 == 0) out[row0 + r] = o + b2[0];
        }
    }
}

extern "C" void kernel_launch(void* const* d_in, const int* in_sizes, int n_in,
                              void* d_out, int out_size, void* d_ws, size_t ws_size,
                              hipStream_t stream) {
    const float* x    = (const float*)d_in[0];
    const int*   mask = (const int*)d_in[1];
    const float* wq   = (const float*)d_in[2];
    const float* bq   = (const float*)d_in[3];
    const float* wk   = (const float*)d_in[4];
    const float* bk   = (const float*)d_in[5];
    const float* wv   = (const float*)d_in[6];
    const float* bv   = (const float*)d_in[7];
    const float* ln_g = (const float*)d_in[8];
    const float* ln_b = (const float*)d_in[9];
    const float* w_ih = (const float*)d_in[10];
    const float* w_hh = (const float*)d_in[11];
    const float* b_ih = (const float*)d_in[12];
    const float* b_hh = (const float*)d_in[13];
    const float* w1   = (const float*)d_in[14];
    const float* b1   = (const float*)d_in[15];
    const float* w2   = (const float*)d_in[16];
    const float* b2   = (const float*)d_in[17];

    float* ws = (float*)d_ws;
    // phase 1 (f32 index units):
    _Float16* Qh  = (_Float16*)ws;                    // f16 [0, 3,932,160)
    _Float16* Kh  = (_Float16*)(ws + 3932160);        // f16 [3,932,160, 7,864,320)
    float*    V   = ws + 7864320;                     // f32 [7,864,320, 15,728,640)
    // phase 2: XP aliases the dead Q/K/V region
    _Float16* XP  = (_Float16*)ws;                    // f16 [0, 23,592,960)
    float* market = ws + 23592960;                    //    15,360 f32
    _Float16* wf16 = (_Float16*)(ws + 23608320);      //    86,016 f16
    _Float16* wqkv = (_Float16*)(ws + 23651328);      //    30,720 f16
    _Float16* whh16= (_Float16*)(ws + 23666688);      //    49,152 f16
    // total ~94.8 MB

    prep_kernel<<<648, 256, 0, stream>>>(w_ih, wq, wk, wv, w_hh, wf16, wqkv, whh16);
    qkv_kernel<<<1920, 256, 0, stream>>>(x, wqkv, bq, bk, bv, Qh, Kh, V);
    attn_kernel<<<240, 512, 0, stream>>>(Qh, Kh, mask, V, market);
    xproj_kernel<<<1920, 512, 0, stream>>>(x, market, ln_g, ln_b, wf16, b_ih, XP);
    gru_kernel<<<128, 512, 0, stream>>>(XP, whh16, b_hh, w1, b1, w2, b2, (float*)d_out);
}

// Round 4
// 356.835 us; speedup vs baseline: 1.0534x; 1.0534x over previous
//
#include <hip/hip_runtime.h>
#include <hip/hip_bf16.h>
#include <math.h>

#define BB 4
#define DD 60
#define SS 512
#define FF 158
#define CC 64
#define HH 128
#define FC 222      // F + C
#define G3 384      // 3H
#define NN 2048     // B*S
#define BDN 240     // B*D

#define L2E  1.44269504f
#define L2E2 2.88539008f
#define QSCALE 0.18033688f   // 0.125 * log2(e)

typedef _Float16 f16x8 __attribute__((ext_vector_type(8)));
typedef float f32x4 __attribute__((ext_vector_type(4)));

// bare v_exp_f32 (2^x) via clang builtin; log2e pre-folded upstream
__device__ __forceinline__ float exp2_hw(float x){ return __builtin_amdgcn_exp2f(x); }
__device__ __forceinline__ float rcp_hw(float x){ return __builtin_amdgcn_rcpf(x); }

// ---- prep: wf16 (384x224) xproj, wqkv (192x160) qkv, whh16 (384x128) gru -------------
// w_ih / w_hh rows are pre-scaled by log2e (gates r,z) or 2*log2e (gate n) so the GRU
// gate transcendentals become bare v_exp_f32 (2^x). Biases scaled at their load sites.
__global__ void prep_kernel(const float* __restrict__ w_ih,
                            const float* __restrict__ wq, const float* __restrict__ wk,
                            const float* __restrict__ wv, const float* __restrict__ w_hh,
                            _Float16* __restrict__ wf16, _Float16* __restrict__ wqkv,
                            _Float16* __restrict__ whh16){
    int idx = blockIdx.x*256 + threadIdx.x;
    if (idx < 384*224){
        int n = idx / 224, k = idx % 224;
        float sc = (n < 256) ? L2E : L2E2;
        wf16[idx] = (k < FC) ? (_Float16)(w_ih[n*FC + k] * sc) : (_Float16)0.0f;
    } else if (idx < 384*224 + 192*160){
        int i2 = idx - 384*224;
        int n = i2 / 160, k = i2 % 160;
        float v = 0.0f;
        if (k < FF){
            if (n < 64)       v = wq[k*CC + n];
            else if (n < 128) v = wk[k*CC + (n-64)];
            else              v = wv[k*CC + (n-128)];
        }
        wqkv[i2] = (_Float16)v;
    } else {
        int i3 = idx - (384*224 + 192*160);
        if (i3 < 384*128){
            int n = i3 / 128;
            float sc = (n < 256) ? L2E : L2E2;
            whh16[i3] = (_Float16)(w_hh[i3] * sc);
        }
    }
}

// ---------------- QKV via f16 MFMA: 64 rows/block, 256 thr (4 waves) ------------------
// Qh is stored pre-scaled by 0.125*log2e so attn's softmax exp is a bare v_exp_f32.
__global__ __launch_bounds__(256) void qkv_kernel(const float* __restrict__ x,
                           const _Float16* __restrict__ wqkv,
                           const float* __restrict__ bq, const float* __restrict__ bk,
                           const float* __restrict__ bv,
                           _Float16* __restrict__ Qh, _Float16* __restrict__ Kh,
                           float* __restrict__ V){
    __shared__ _Float16 xa[5][64][40];   // fragment layout, 25.6 KB
    int tid  = threadIdx.x;
    int lane = tid & 63, wv = tid >> 6;
    int col  = lane & 15, quad = lane >> 4;
    int row0 = blockIdx.x * 64;

    f16x8 bfr[3][5];
    #pragma unroll
    for (int nt = 0; nt < 3; ++nt){
        int n = wv*48 + nt*16 + col;
        #pragma unroll
        for (int kq = 0; kq < 5; ++kq)
            bfr[nt][kq] = *(const f16x8*)&wqkv[n*160 + kq*32 + quad*8];
    }

    for (int i = tid; i < 64*160; i += 256){
        int r = i / 160, k = i % 160;
        float v = (k < FF) ? x[(size_t)(row0 + r)*FF + k] : 0.0f;
        xa[k >> 5][r][k & 31] = (_Float16)v;
    }
    __syncthreads();

    float bias[3];
    #pragma unroll
    for (int nt = 0; nt < 3; ++nt){
        int n = wv*48 + nt*16 + col;
        bias[nt] = (n < 64) ? bq[n] : (n < 128 ? bk[n-64] : bv[n-128]);
    }

    #pragma unroll 1
    for (int mt = 0; mt < 4; ++mt){
        f16x8 a[5];
        #pragma unroll
        for (int kq = 0; kq < 5; ++kq)
            a[kq] = *(const f16x8*)&xa[kq][mt*16 + col][quad*8];
        #pragma unroll
        for (int nt = 0; nt < 3; ++nt){
            f32x4 c = {0.0f, 0.0f, 0.0f, 0.0f};
            #pragma unroll
            for (int kq = 0; kq < 5; ++kq)
                c = __builtin_amdgcn_mfma_f32_16x16x32_f16(a[kq], bfr[nt][kq], c, 0, 0, 0);
            int n = wv*48 + nt*16 + col;
            #pragma unroll
            for (int reg = 0; reg < 4; ++reg){
                int row = row0 + mt*16 + quad*4 + reg;
                float val = c[reg] + bias[nt];
                if (n < 64)       Qh[(size_t)row*CC + n]       = (_Float16)(val * QSCALE);
                else if (n < 128) Kh[(size_t)row*CC + (n-64)]  = (_Float16)val;
                else              V [(size_t)row*CC + (n-128)] = val;
            }
        }
    }
}

// ---------------- attention + fused market: one block per bd --------------------------
// Q pre-scaled: exp(S/8) == 2^(c) with c = (0.125*log2e*Q)@K -> bare v_exp_f32.
__global__ __launch_bounds__(512) void attn_kernel(const _Float16* __restrict__ Qh,
                                                   const _Float16* __restrict__ Kh,
                                                   const int* __restrict__ mask,
                                                   const float* __restrict__ V,
                                                   float* __restrict__ market){
    __shared__ _Float16 kf[2][512][32];   // 64 KB
    __shared__ float w_sh[512];
    __shared__ float mk_lds[512];

    int tid  = threadIdx.x;
    int bd   = blockIdx.x;
    int lane = tid & 63, wv = tid >> 6;
    int col  = lane & 15, quad = lane >> 4;

    const _Float16* qb = Qh + (size_t)(bd*SS)*CC;
    const _Float16* kb = Kh + (size_t)(bd*SS)*CC;

    {
        int t = tid;
        w_sh[t] = 0.0f;
        mk_lds[t] = (mask[bd*SS + t] != 0) ? 1.0f : 0.0f;
    }
    for (int i = tid; i < 4096; i += 512){
        int t = i >> 3, ch = i & 7;
        *(f16x8*)&kf[ch >> 2][t][(ch & 3)*8] = *(const f16x8*)&kb[t*CC + ch*8];
    }

    f16x8 a0[4], a1[4];
    #pragma unroll
    for (int af = 0; af < 4; ++af){
        int row = wv*64 + af*16 + col;
        a0[af] = *(const f16x8*)&qb[row*CC + quad*8];
        a1[af] = *(const f16x8*)&qb[row*CC + 32 + quad*8];
    }
    __syncthreads();

    // ---- pass 0: row sums l ----
    float lacc[4][4] = {{0,0,0,0},{0,0,0,0},{0,0,0,0},{0,0,0,0}};
    #pragma unroll 2
    for (int kt = 0; kt < 32; ++kt){
        f16x8 b0 = *(const f16x8*)&kf[0][kt*16 + col][quad*8];
        f16x8 b1 = *(const f16x8*)&kf[1][kt*16 + col][quad*8];
        float mkv = mk_lds[kt*16 + col];
        #pragma unroll
        for (int af = 0; af < 4; ++af){
            f32x4 c = {0.0f, 0.0f, 0.0f, 0.0f};
            c = __builtin_amdgcn_mfma_f32_16x16x32_f16(a0[af], b0, c, 0, 0, 0);
            c = __builtin_amdgcn_mfma_f32_16x16x32_f16(a1[af], b1, c, 0, 0, 0);
            #pragma unroll
            for (int reg = 0; reg < 4; ++reg)
                lacc[af][reg] += exp2_hw(c[reg]) * mkv;
        }
    }
    float crv[4][4];
    #pragma unroll
    for (int af = 0; af < 4; ++af){
        #pragma unroll
        for (int reg = 0; reg < 4; ++reg){
            float l = lacc[af][reg];
            l += __shfl_xor(l, 1, 64);
            l += __shfl_xor(l, 2, 64);
            l += __shfl_xor(l, 4, 64);
            l += __shfl_xor(l, 8, 64);
            int row = wv*64 + af*16 + quad*4 + reg;
            crv[af][reg] = mk_lds[row] * rcp_hw(l);
        }
    }

    // ---- pass 1: accumulate W columns ----
    #pragma unroll 2
    for (int kt = 0; kt < 32; ++kt){
        f16x8 b0 = *(const f16x8*)&kf[0][kt*16 + col][quad*8];
        f16x8 b1 = *(const f16x8*)&kf[1][kt*16 + col][quad*8];
        float s = 0.0f;
        #pragma unroll
        for (int af = 0; af < 4; ++af){
            f32x4 c = {0.0f, 0.0f, 0.0f, 0.0f};
            c = __builtin_amdgcn_mfma_f32_16x16x32_f16(a0[af], b0, c, 0, 0, 0);
            c = __builtin_amdgcn_mfma_f32_16x16x32_f16(a1[af], b1, c, 0, 0, 0);
            #pragma unroll
            for (int reg = 0; reg < 4; ++reg)
                s = fmaf(exp2_hw(c[reg]), crv[af][reg], s);
        }
        s += __shfl_xor(s, 16, 64);
        s += __shfl_xor(s, 32, 64);
        if (quad == 0)
            atomicAdd(&w_sh[kt*16 + col], s);
    }
    __syncthreads();   // w_sh final; kf reads complete -> reuse kf as scratch

    // ---- fused market ----
    float* msum = (float*)kf;
    {
        int c = tid & 63, grp = tid >> 6;
        const float* vb = V + (size_t)(bd*SS)*CC;
        float acc = 0.0f;
        int t0 = grp*64;
        #pragma unroll 4
        for (int t = t0; t < t0 + 64; ++t)
            acc = fmaf(w_sh[t]*mk_lds[t], vb[(size_t)t*CC + c], acc);
        msum[grp*64 + c] = acc;
    }
    __syncthreads();
    if (tid < 64){
        float s = 0.0f;
        #pragma unroll
        for (int g = 0; g < 8; ++g) s += msum[g*64 + tid];
        float cnt = 0.0f;
        #pragma unroll
        for (int j = 0; j < 8; ++j) cnt += mk_lds[tid + 64*j];
        #pragma unroll
        for (int o = 1; o < 64; o <<= 1) cnt += __shfl_xor(cnt, o, 64);
        market[bd*CC + tid] = s * rcp_hw(fmaxf(cnt, 1.0f));
    }
}

// ---------------- fused LN + x_proj f16 MFMA GEMM -------------------------------------
// b_ih scaled by log2e / 2*log2e per gate row (matches wf16 row scaling).
__global__ __launch_bounds__(512, 2) void xproj_kernel(const float* __restrict__ x,
                             const float* __restrict__ market,
                             const float* __restrict__ ln_g, const float* __restrict__ ln_b,
                             const _Float16* __restrict__ wf16, const float* __restrict__ b_ih,
                             _Float16* __restrict__ XP){
    __shared__ _Float16 aug[7][64][32];   // 28 KB
    int tid  = threadIdx.x;
    int lane = tid & 63, wv = tid >> 6;
    int col  = lane & 15, quad = lane >> 4;
    int row0 = blockIdx.x * 64;

    f16x8 bfr[3][7];
    #pragma unroll
    for (int nt = 0; nt < 3; ++nt){
        int n = wv*48 + nt*16 + col;
        #pragma unroll
        for (int kq = 0; kq < 7; ++kq)
            bfr[nt][kq] = *(const f16x8*)&wf16[n*224 + kq*32 + quad*8];
    }

    {
        int wrow = wv*8 + (lane >> 3);
        int g    = lane & 7;
        int row  = row0 + wrow;
        int d = row / NN, n = row % NN;
        int b = n >> 9, s = n & 511;
        const float* xr = &x[((size_t)((b*DD + d)*SS) + s)*FF];
        const float* mr = &market[(b*DD + d)*CC];
        float v[28];
        float sum = 0.0f, sq = 0.0f;
        #pragma unroll
        for (int j = 0; j < 28; ++j){
            int f = g + 8*j;
            float vv = 0.0f;
            if (f < FF) vv = xr[f];
            else if (f < FC) vv = mr[f - FF];
            v[j] = vv;
            sum += vv; sq += vv*vv;
        }
        sum += __shfl_xor(sum,1,64); sq += __shfl_xor(sq,1,64);
        sum += __shfl_xor(sum,2,64); sq += __shfl_xor(sq,2,64);
        sum += __shfl_xor(sum,4,64); sq += __shfl_xor(sq,4,64);
        float mu   = sum * (1.0f/222.0f);
        float var  = sq * (1.0f/222.0f) - mu*mu;
        float rstd = rsqrtf(var + 1e-5f);
        #pragma unroll
        for (int j = 0; j < 28; ++j){
            int f = g + 8*j;
            float val = (f < FC) ? ((v[j]-mu)*rstd*ln_g[f] + ln_b[f]) : 0.0f;
            aug[f>>5][wrow][f&31] = (_Float16)val;
        }
    }
    __syncthreads();

    float bias[3];
    #pragma unroll
    for (int nt = 0; nt < 3; ++nt){
        int n = wv*48 + nt*16 + col;
        bias[nt] = b_ih[n] * ((n < 256) ? L2E : L2E2);
    }
    #pragma unroll 1
    for (int mt = 0; mt < 4; ++mt){
        f16x8 a[7];
        #pragma unroll
        for (int kq = 0; kq < 7; ++kq)
            a[kq] = *(const f16x8*)&aug[kq][mt*16 + col][quad*8];
        #pragma unroll
        for (int nt = 0; nt < 3; ++nt){
            f32x4 c = {0.0f, 0.0f, 0.0f, 0.0f};
            #pragma unroll
            for (int kq = 0; kq < 7; ++kq)
                c = __builtin_amdgcn_mfma_f32_16x16x32_f16(a[kq], bfr[nt][kq], c, 0, 0, 0);
            int nn = wv*48 + nt*16 + col;
            #pragma unroll
            for (int reg = 0; reg < 4; ++reg){
                int m = quad*4 + reg;
                XP[(size_t)(row0 + mt*16 + m)*G3 + nn] = (_Float16)(c[reg] + bias[nt]);
            }
        }
    }
}

// ---------------- persistent GRU v4: 1 wave/SIMD, slim exp2/rcp gates -----------------
// 128 blocks x 256 thr (4 waves) -> 1 block/CU, 1 wave/SIMD: halves per-SIMD VALU
// contention vs 8-wave v3. Wave w owns gate cols {g*128 + w*32 + [0,32)} for g=0..2:
// 24 MFMAs/step/wave, gates fully in registers (C layout col=lane&15, row=quad*4+reg).
// Weights pre-scaled by log2e (r,z) / 2*log2e (n) => sigmoid = rcp(1+exp2(-a)),
// tanh = 1-2*rcp(exp2(a')+1): bare v_exp_f32 + v_rcp_f32, no divide refinement.
// Barrier: raw lgkmcnt(0)+s_barrier (XP prefetch loads stay in flight).
#define XLOAD(dst, base_) do{                                                   \
    _Pragma("unroll") for (int hf_ = 0; hf_ < 2; ++hf_)                         \
    _Pragma("unroll") for (int rg_ = 0; rg_ < 4; ++rg_)                         \
    _Pragma("unroll") for (int g_ = 0; g_ < 3; ++g_)                            \
        dst[hf_][rg_][g_] = (base_)[rg_*G3 + g_*HH + hf_*16];                   \
}while(0)

#define BARRIER_NODRAIN() asm volatile("s_waitcnt lgkmcnt(0)\ns_barrier" ::: "memory")

#define GRU_STEP(PRD, PWR, XC, XPF, DOPF) do{                                   \
    if (DOPF) { XLOAD(XPF, xp_d + 2*DSTR); }                                    \
    f16x8 a_[4];                                                                \
    _Pragma("unroll") for (int kq = 0; kq < 4; ++kq)                            \
        a_[kq] = *(const f16x8*)&hfrag[PRD][kq][col][quad*8];                   \
    f32x4 c_[3][2];                                                             \
    _Pragma("unroll") for (int g = 0; g < 3; ++g)                               \
    _Pragma("unroll") for (int hf = 0; hf < 2; ++hf){                           \
        f32x4 acc = {0.0f, 0.0f, 0.0f, 0.0f};                                   \
        _Pragma("unroll") for (int kq = 0; kq < 4; ++kq)                        \
            acc = __builtin_amdgcn_mfma_f32_16x16x32_f16(a_[kq], bfr[g][hf][kq], acc, 0,0,0); \
        c_[g][hf] = acc;                                                        \
    }                                                                           \
    _Pragma("unroll") for (int hf = 0; hf < 2; ++hf)                            \
    _Pragma("unroll") for (int rg = 0; rg < 4; ++rg){                           \
        float r_ = rcp_hw(1.0f + exp2_hw(-((float)XC[hf][rg][0] + c_[0][hf][rg] + bh[0][hf]))); \
        float z_ = rcp_hw(1.0f + exp2_hw(-((float)XC[hf][rg][1] + c_[1][hf][rg] + bh[1][hf]))); \
        float e_ = exp2_hw((float)XC[hf][rg][2] + r_*(c_[2][hf][rg] + bh[2][hf])); \
        float n_ = 1.0f - 2.0f*rcp_hw(e_ + 1.0f);                               \
        float h_ = n_ + z_*(hcur[hf][rg] - n_);                                 \
        hcur[hf][rg] = h_;                                                      \
        hfrag[PWR][w][quad*4 + rg][hf*16 + col] = (_Float16)h_;                 \
    }                                                                           \
    xp_d += DSTR;                                                               \
    BARRIER_NODRAIN();                                                          \
}while(0)

__global__ __launch_bounds__(256, 1) void gru_kernel(const _Float16* __restrict__ XP,
                                                     const _Float16* __restrict__ whh16,
                                                     const float* __restrict__ b_hh,
                                                     const float* __restrict__ w1, const float* __restrict__ b1,
                                                     const float* __restrict__ w2, const float* __restrict__ b2,
                                                     float* __restrict__ out){
    __shared__ _Float16 hfrag[2][4][16][40];  // 10 KB, MFMA-A fragment layout, dbuf, padded
    __shared__ float h_sh[16][132];           // final h for head (padded)

    const int tid  = threadIdx.x;
    const int lane = tid & 63, w = tid >> 6;      // 4 waves
    const int col  = lane & 15, quad = lane >> 4;
    const int row0 = blockIdx.x * 16;             // 16 seqs/block

    // zero h buffer (h0 = 0)
    for (int i = tid; i < 2*4*16*40; i += 256)
        ((_Float16*)hfrag)[i] = (_Float16)0.0f;

    // W_hh B-fragments: n = g*128 + w*32 + hf*16 + col, k = kq*32 + quad*8 + j
    f16x8 bfr[3][2][4];
    #pragma unroll
    for (int g = 0; g < 3; ++g)
    #pragma unroll
    for (int hf = 0; hf < 2; ++hf){
        int n = g*HH + w*32 + hf*16 + col;
        #pragma unroll
        for (int kq = 0; kq < 4; ++kq)
            bfr[g][hf][kq] = *(const f16x8*)&whh16[(size_t)n*HH + kq*32 + quad*8];
    }

    float bh[3][2];
    #pragma unroll
    for (int g = 0; g < 3; ++g)
    #pragma unroll
    for (int hf = 0; hf < 2; ++hf)
        bh[g][hf] = b_hh[g*HH + w*32 + hf*16 + col] * ((g < 2) ? L2E : L2E2);

    const size_t DSTR = (size_t)NN * G3;
    // thread's 24 XP values per step: seq = row0+quad*4+rg, col = g*128 + w*32 + hf*16 + col
    const _Float16* xp_d = XP + (size_t)(row0 + quad*4)*G3 + (w*32 + col);

    _Float16 xA[2][4][3], xB[2][4][3], xC[2][4][3];
    XLOAD(xA, xp_d);            // d = 0
    XLOAD(xB, xp_d + DSTR);     // d = 1

    float hcur[2][4] = {{0,0,0,0},{0,0,0,0}};
    __syncthreads();            // once: hfrag zero-init visible

    #pragma unroll 1
    for (int ch = 0; ch < 10; ++ch){
        const int pf = (ch < 9);          // last chunk: d+2 would be >= 60
        GRU_STEP(0, 1, xA, xC, 1);
        GRU_STEP(1, 0, xB, xA, 1);
        GRU_STEP(0, 1, xC, xB, 1);
        GRU_STEP(1, 0, xA, xC, 1);
        GRU_STEP(0, 1, xB, xA, pf);
        GRU_STEP(1, 0, xC, xB, pf);
    }

    #pragma unroll
    for (int hf = 0; hf < 2; ++hf)
    #pragma unroll
    for (int rg = 0; rg < 4; ++rg)
        h_sh[quad*4 + rg][w*32 + hf*16 + col] = hcur[hf][rg];
    __syncthreads();

    // ---- output head: 256 thr -> 4 rows in parallel, 4 passes ----
    {
        int c2 = tid & 63;
        int rb = tid >> 6;
        #pragma unroll
        for (int rr = 0; rr < 4; ++rr){
            int r = rb*4 + rr;
            float acc = 0.0f;
            #pragma unroll 8
            for (int k = 0; k < 128; ++k)
                acc = fmaf(h_sh[r][k], w1[k*64 + c2], acc);
            float hid = fmaxf(acc + b1[c2], 0.0f);
            float o = hid * w2[c2];
            #pragma unroll
            for (int off = 1; off < 64; off <<= 1) o += __shfl_xor(o, off, 64);
            if (c2 == 0) out[row0 + r] = o + b2[0];
        }
    }
}

extern "C" void kernel_launch(void* const* d_in, const int* in_sizes, int n_in,
                              void* d_out, int out_size, void* d_ws, size_t ws_size,
                              hipStream_t stream) {
    const float* x    = (const float*)d_in[0];
    const int*   mask = (const int*)d_in[1];
    const float* wq   = (const float*)d_in[2];
    const float* bq   = (const float*)d_in[3];
    const float* wk   = (const float*)d_in[4];
    const float* bk   = (const float*)d_in[5];
    const float* wv   = (const float*)d_in[6];
    const float* bv   = (const float*)d_in[7];
    const float* ln_g = (const float*)d_in[8];
    const float* ln_b = (const float*)d_in[9];
    const float* w_ih = (const float*)d_in[10];
    const float* w_hh = (const float*)d_in[11];
    const float* b_ih = (const float*)d_in[12];
    const float* b_hh = (const float*)d_in[13];
    const float* w1   = (const float*)d_in[14];
    const float* b1   = (const float*)d_in[15];
    const float* w2   = (const float*)d_in[16];
    const float* b2   = (const float*)d_in[17];

    float* ws = (float*)d_ws;
    // phase 1 (f32 index units):
    _Float16* Qh  = (_Float16*)ws;                    // f16 [0, 3,932,160)
    _Float16* Kh  = (_Float16*)(ws + 3932160);        // f16 [3,932,160, 7,864,320)
    float*    V   = ws + 7864320;                     // f32 [7,864,320, 15,728,640)
    // phase 2: XP aliases the dead Q/K/V region
    _Float16* XP  = (_Float16*)ws;                    // f16 [0, 23,592,960)
    float* market = ws + 23592960;                    //    15,360 f32
    _Float16* wf16 = (_Float16*)(ws + 23608320);      //    86,016 f16
    _Float16* wqkv = (_Float16*)(ws + 23651328);      //    30,720 f16
    _Float16* whh16= (_Float16*)(ws + 23666688);      //    49,152 f16
    // total ~94.8 MB

    prep_kernel<<<648, 256, 0, stream>>>(w_ih, wq, wk, wv, w_hh, wf16, wqkv, whh16);
    qkv_kernel<<<1920, 256, 0, stream>>>(x, wqkv, bq, bk, bv, Qh, Kh, V);
    attn_kernel<<<240, 512, 0, stream>>>(Qh, Kh, mask, V, market);
    xproj_kernel<<<1920, 512, 0, stream>>>(x, market, ln_g, ln_b, wf16, b_ih, XP);
    gru_kernel<<<128, 256, 0, stream>>>(XP, whh16, b_hh, w1, b1, w2, b2, (float*)d_out);
}

// Round 5
// 346.812 us; speedup vs baseline: 1.0839x; 1.0289x over previous
//
#include <hip/hip_runtime.h>
#include <hip/hip_bf16.h>
#include <math.h>

#define BB 4
#define DD 60
#define SS 512
#define FF 158
#define CC 64
#define HH 128
#define FC 222      // F + C
#define G3 384      // 3H
#define NN 2048     // B*S
#define BDN 240     // B*D

#define L2E  1.44269504f
#define L2E2 2.88539008f
#define QSCALE 0.18033688f   // 0.125 * log2(e)

typedef _Float16 f16x8 __attribute__((ext_vector_type(8)));
typedef float f32x4 __attribute__((ext_vector_type(4)));

// bare v_exp_f32 (2^x) via clang builtin; log2e pre-folded upstream
__device__ __forceinline__ float exp2_hw(float x){ return __builtin_amdgcn_exp2f(x); }
__device__ __forceinline__ float rcp_hw(float x){ return __builtin_amdgcn_rcpf(x); }

// ---- prep: wf16 (384x224) xproj, wqk (128x160) qk, whh16 (384x128) gru ---------------
// w_ih / w_hh rows are pre-scaled by log2e (gates r,z) or 2*log2e (gate n) so the GRU
// gate transcendentals become bare v_exp_f32 (2^x). Biases scaled at their load sites.
__global__ void prep_kernel(const float* __restrict__ w_ih,
                            const float* __restrict__ wq, const float* __restrict__ wk,
                            const float* __restrict__ w_hh,
                            _Float16* __restrict__ wf16, _Float16* __restrict__ wqk,
                            _Float16* __restrict__ whh16){
    int idx = blockIdx.x*256 + threadIdx.x;
    if (idx < 384*224){
        int n = idx / 224, k = idx % 224;
        float sc = (n < 256) ? L2E : L2E2;
        wf16[idx] = (k < FC) ? (_Float16)(w_ih[n*FC + k] * sc) : (_Float16)0.0f;
    } else if (idx < 384*224 + 128*160){
        int i2 = idx - 384*224;
        int n = i2 / 160, k = i2 % 160;
        float v = 0.0f;
        if (k < FF)
            v = (n < 64) ? wq[k*CC + n] : wk[k*CC + (n-64)];
        wqk[i2] = (_Float16)v;
    } else {
        int i3 = idx - (384*224 + 128*160);
        if (i3 < 384*128){
            int n = i3 / 128;
            float sc = (n < 256) ? L2E : L2E2;
            whh16[i3] = (_Float16)(w_hh[i3] * sc);
        }
    }
}

// ---------------- QK via f16 MFMA: 64 rows/block, 256 thr (4 waves) -------------------
// V eliminated (attn computes market = (w~@x)@wv directly). N=128: wave owns 32 cols.
// Staging: block's x slice (64 rows x 158 f32) is contiguous & 16B-aligned ->
// 10 coalesced dwordx4 loads/thread, scatter to fragment LDS via divmod-158.
// Qh is stored pre-scaled by 0.125*log2e so attn's softmax exp is a bare v_exp_f32.
__global__ __launch_bounds__(256) void qk_kernel(const float* __restrict__ x,
                           const _Float16* __restrict__ wqk,
                           const float* __restrict__ bq, const float* __restrict__ bk,
                           _Float16* __restrict__ Qh, _Float16* __restrict__ Kh){
    __shared__ _Float16 xa[5][64][40];   // fragment layout, 25.6 KB
    int tid  = threadIdx.x;
    int lane = tid & 63, wv = tid >> 6;
    int col  = lane & 15, quad = lane >> 4;
    int row0 = blockIdx.x * 64;

    f16x8 bfr[2][5];
    #pragma unroll
    for (int nt = 0; nt < 2; ++nt){
        int n = wv*32 + nt*16 + col;
        #pragma unroll
        for (int kq = 0; kq < 5; ++kq)
            bfr[nt][kq] = *(const f16x8*)&wqk[n*160 + kq*32 + quad*8];
    }

    // zero the two pad k-slots (k=158,159 -> xa[4][r][30/31]); rest fully written below
    if (tid < 128){
        int r = tid >> 1;
        xa[4][r][30 + (tid & 1)] = (_Float16)0.0f;
    }
    // vectorized staging: 64*158 = 10112 f32 = 2528 float4 (16B-aligned: row0*632 % 16 == 0)
    {
        const float4* xb4 = (const float4*)(x + (size_t)row0*FF);
        #pragma unroll
        for (int j = 0; j < 10; ++j){
            int i = tid + j*256;
            if (i < 2528){
                float4 v = xb4[i];
                int base = i*4;
                #pragma unroll
                for (int e = 0; e < 4; ++e){
                    int idx = base + e;
                    int r = idx / 158;            // magic-mul
                    int k = idx - r*158;
                    xa[k >> 5][r][k & 31] = (_Float16)((&v.x)[e]);
                }
            }
        }
    }
    __syncthreads();

    float bias[2];
    #pragma unroll
    for (int nt = 0; nt < 2; ++nt){
        int n = wv*32 + nt*16 + col;
        bias[nt] = (n < 64) ? bq[n] : bk[n-64];
    }

    #pragma unroll 1
    for (int mt = 0; mt < 4; ++mt){
        f16x8 a[5];
        #pragma unroll
        for (int kq = 0; kq < 5; ++kq)
            a[kq] = *(const f16x8*)&xa[kq][mt*16 + col][quad*8];
        #pragma unroll
        for (int nt = 0; nt < 2; ++nt){
            f32x4 c = {0.0f, 0.0f, 0.0f, 0.0f};
            #pragma unroll
            for (int kq = 0; kq < 5; ++kq)
                c = __builtin_amdgcn_mfma_f32_16x16x32_f16(a[kq], bfr[nt][kq], c, 0, 0, 0);
            int n = wv*32 + nt*16 + col;
            #pragma unroll
            for (int reg = 0; reg < 4; ++reg){
                int row = row0 + mt*16 + quad*4 + reg;
                float val = c[reg] + bias[nt];
                if (n < 64) Qh[(size_t)row*CC + n]      = (_Float16)(val * QSCALE);
                else        Kh[(size_t)row*CC + (n-64)] = (_Float16)val;
            }
        }
    }
}

// ---------------- attention + fused market (V-free): one block per bd -----------------
// Q pre-scaled: exp(S/8) == 2^c -> bare v_exp_f32.
// market = (w~ @ x_bd) @ wv + (sum w~)*bv, all f32 (w~[t] = w_sh[t]*mask[t]).
__global__ __launch_bounds__(512) void attn_kernel(const _Float16* __restrict__ Qh,
                                                   const _Float16* __restrict__ Kh,
                                                   const int* __restrict__ mask,
                                                   const float* __restrict__ x,
                                                   const float* __restrict__ wv,
                                                   const float* __restrict__ bv,
                                                   float* __restrict__ market){
    __shared__ _Float16 kf[2][512][32];   // 64 KB
    __shared__ float w_sh[512];
    __shared__ float mk_lds[512];

    int tid  = threadIdx.x;
    int bd   = blockIdx.x;
    int lane = tid & 63, wvw = tid >> 6;
    int col  = lane & 15, quad = lane >> 4;

    const _Float16* qb = Qh + (size_t)(bd*SS)*CC;
    const _Float16* kb = Kh + (size_t)(bd*SS)*CC;

    {
        int t = tid;
        w_sh[t] = 0.0f;
        mk_lds[t] = (mask[bd*SS + t] != 0) ? 1.0f : 0.0f;
    }
    for (int i = tid; i < 4096; i += 512){
        int t = i >> 3, ch = i & 7;
        *(f16x8*)&kf[ch >> 2][t][(ch & 3)*8] = *(const f16x8*)&kb[t*CC + ch*8];
    }

    f16x8 a0[4], a1[4];
    #pragma unroll
    for (int af = 0; af < 4; ++af){
        int row = wvw*64 + af*16 + col;
        a0[af] = *(const f16x8*)&qb[row*CC + quad*8];
        a1[af] = *(const f16x8*)&qb[row*CC + 32 + quad*8];
    }
    __syncthreads();

    // ---- pass 0: row sums l ----
    float lacc[4][4] = {{0,0,0,0},{0,0,0,0},{0,0,0,0},{0,0,0,0}};
    #pragma unroll 2
    for (int kt = 0; kt < 32; ++kt){
        f16x8 b0 = *(const f16x8*)&kf[0][kt*16 + col][quad*8];
        f16x8 b1 = *(const f16x8*)&kf[1][kt*16 + col][quad*8];
        float mkv = mk_lds[kt*16 + col];
        #pragma unroll
        for (int af = 0; af < 4; ++af){
            f32x4 c = {0.0f, 0.0f, 0.0f, 0.0f};
            c = __builtin_amdgcn_mfma_f32_16x16x32_f16(a0[af], b0, c, 0, 0, 0);
            c = __builtin_amdgcn_mfma_f32_16x16x32_f16(a1[af], b1, c, 0, 0, 0);
            #pragma unroll
            for (int reg = 0; reg < 4; ++reg)
                lacc[af][reg] += exp2_hw(c[reg]) * mkv;
        }
    }
    float crv[4][4];
    #pragma unroll
    for (int af = 0; af < 4; ++af){
        #pragma unroll
        for (int reg = 0; reg < 4; ++reg){
            float l = lacc[af][reg];
            l += __shfl_xor(l, 1, 64);
            l += __shfl_xor(l, 2, 64);
            l += __shfl_xor(l, 4, 64);
            l += __shfl_xor(l, 8, 64);
            int row = wvw*64 + af*16 + quad*4 + reg;
            crv[af][reg] = mk_lds[row] * rcp_hw(l);
        }
    }

    // ---- pass 1: accumulate W columns ----
    #pragma unroll 2
    for (int kt = 0; kt < 32; ++kt){
        f16x8 b0 = *(const f16x8*)&kf[0][kt*16 + col][quad*8];
        f16x8 b1 = *(const f16x8*)&kf[1][kt*16 + col][quad*8];
        float s = 0.0f;
        #pragma unroll
        for (int af = 0; af < 4; ++af){
            f32x4 c = {0.0f, 0.0f, 0.0f, 0.0f};
            c = __builtin_amdgcn_mfma_f32_16x16x32_f16(a0[af], b0, c, 0, 0, 0);
            c = __builtin_amdgcn_mfma_f32_16x16x32_f16(a1[af], b1, c, 0, 0, 0);
            #pragma unroll
            for (int reg = 0; reg < 4; ++reg)
                s = fmaf(exp2_hw(c[reg]), crv[af][reg], s);
        }
        s += __shfl_xor(s, 16, 64);
        s += __shfl_xor(s, 32, 64);
        if (quad == 0)
            atomicAdd(&w_sh[kt*16 + col], s);
    }
    __syncthreads();   // w_sh final; kf reads complete -> reuse kf as scratch

    // ---- fused market, V-free ----
    w_sh[tid] *= mk_lds[tid];          // w~[t]
    __syncthreads();

    float* part = (float*)kf;          // 512-float scratch in dead kf
    {
        int tg = tid >> 8;             // t-half: 0/1
        int kk = tid & 255;            // feature column
        float acc = 0.0f;
        if (kk < FF){
            const float* xb = x + ((size_t)bd*SS + tg*256)*FF + kk;
            #pragma unroll 8
            for (int t = 0; t < 256; ++t)
                acc = fmaf(w_sh[tg*256 + t], xb[(size_t)t*FF], acc);
        }
        part[tg*256 + kk] = acc;
    }
    __syncthreads();
    if (tid < 64){
        int c = tid;
        float m = 0.0f;
        for (int k = 0; k < FF; ++k){
            float y = part[k] + part[256 + k];   // LDS broadcast (uniform addr)
            m = fmaf(y, wv[k*CC + c], m);
        }
        float cnt = 0.0f, sw = 0.0f;
        #pragma unroll
        for (int j = 0; j < 8; ++j){
            cnt += mk_lds[c + 64*j];
            sw  += w_sh[c + 64*j];
        }
        #pragma unroll
        for (int o = 1; o < 64; o <<= 1){
            cnt += __shfl_xor(cnt, o, 64);
            sw  += __shfl_xor(sw,  o, 64);
        }
        market[bd*CC + c] = (m + sw*bv[c]) * rcp_hw(fmaxf(cnt, 1.0f));
    }
}

// ---------------- fused LN + x_proj f16 MFMA GEMM -------------------------------------
// b_ih scaled by log2e / 2*log2e per gate row (matches wf16 row scaling).
__global__ __launch_bounds__(512, 2) void xproj_kernel(const float* __restrict__ x,
                             const float* __restrict__ market,
                             const float* __restrict__ ln_g, const float* __restrict__ ln_b,
                             const _Float16* __restrict__ wf16, const float* __restrict__ b_ih,
                             _Float16* __restrict__ XP){
    __shared__ _Float16 aug[7][64][32];   // 28 KB
    int tid  = threadIdx.x;
    int lane = tid & 63, wv = tid >> 6;
    int col  = lane & 15, quad = lane >> 4;
    int row0 = blockIdx.x * 64;

    f16x8 bfr[3][7];
    #pragma unroll
    for (int nt = 0; nt < 3; ++nt){
        int n = wv*48 + nt*16 + col;
        #pragma unroll
        for (int kq = 0; kq < 7; ++kq)
            bfr[nt][kq] = *(const f16x8*)&wf16[n*224 + kq*32 + quad*8];
    }

    {
        int wrow = wv*8 + (lane >> 3);
        int g    = lane & 7;
        int row  = row0 + wrow;
        int d = row / NN, n = row % NN;
        int b = n >> 9, s = n & 511;
        const float* xr = &x[((size_t)((b*DD + d)*SS) + s)*FF];
        const float* mr = &market[(b*DD + d)*CC];
        float v[28];
        float sum = 0.0f, sq = 0.0f;
        #pragma unroll
        for (int j = 0; j < 28; ++j){
            int f = g + 8*j;
            float vv = 0.0f;
            if (f < FF) vv = xr[f];
            else if (f < FC) vv = mr[f - FF];
            v[j] = vv;
            sum += vv; sq += vv*vv;
        }
        sum += __shfl_xor(sum,1,64); sq += __shfl_xor(sq,1,64);
        sum += __shfl_xor(sum,2,64); sq += __shfl_xor(sq,2,64);
        sum += __shfl_xor(sum,4,64); sq += __shfl_xor(sq,4,64);
        float mu   = sum * (1.0f/222.0f);
        float var  = sq * (1.0f/222.0f) - mu*mu;
        float rstd = rsqrtf(var + 1e-5f);
        #pragma unroll
        for (int j = 0; j < 28; ++j){
            int f = g + 8*j;
            float val = (f < FC) ? ((v[j]-mu)*rstd*ln_g[f] + ln_b[f]) : 0.0f;
            aug[f>>5][wrow][f&31] = (_Float16)val;
        }
    }
    __syncthreads();

    float bias[3];
    #pragma unroll
    for (int nt = 0; nt < 3; ++nt){
        int n = wv*48 + nt*16 + col;
        bias[nt] = b_ih[n] * ((n < 256) ? L2E : L2E2);
    }
    #pragma unroll 1
    for (int mt = 0; mt < 4; ++mt){
        f16x8 a[7];
        #pragma unroll
        for (int kq = 0; kq < 7; ++kq)
            a[kq] = *(const f16x8*)&aug[kq][mt*16 + col][quad*8];
        #pragma unroll
        for (int nt = 0; nt < 3; ++nt){
            f32x4 c = {0.0f, 0.0f, 0.0f, 0.0f};
            #pragma unroll
            for (int kq = 0; kq < 7; ++kq)
                c = __builtin_amdgcn_mfma_f32_16x16x32_f16(a[kq], bfr[nt][kq], c, 0, 0, 0);
            int nn = wv*48 + nt*16 + col;
            #pragma unroll
            for (int reg = 0; reg < 4; ++reg){
                int m = quad*4 + reg;
                XP[(size_t)(row0 + mt*16 + m)*G3 + nn] = (_Float16)(c[reg] + bias[nt]);
            }
        }
    }
}

// ---------------- persistent GRU v4: 1 wave/SIMD, slim exp2/rcp gates -----------------
// 128 blocks x 256 thr (4 waves) -> 1 block/CU, 1 wave/SIMD. Wave w owns gate cols
// {g*128 + w*32 + [0,32)}: 24 MFMAs/step/wave, gates fully in registers.
// Weights pre-scaled by log2e (r,z) / 2*log2e (n).
// Barrier: raw lgkmcnt(0)+s_barrier (XP prefetch loads stay in flight).
#define XLOAD(dst, base_) do{                                                   \
    _Pragma("unroll") for (int hf_ = 0; hf_ < 2; ++hf_)                         \
    _Pragma("unroll") for (int rg_ = 0; rg_ < 4; ++rg_)                         \
    _Pragma("unroll") for (int g_ = 0; g_ < 3; ++g_)                            \
        dst[hf_][rg_][g_] = (base_)[rg_*G3 + g_*HH + hf_*16];                   \
}while(0)

#define BARRIER_NODRAIN() asm volatile("s_waitcnt lgkmcnt(0)\ns_barrier" ::: "memory")

#define GRU_STEP(PRD, PWR, XC, XPF, DOPF) do{                                   \
    if (DOPF) { XLOAD(XPF, xp_d + 2*DSTR); }                                    \
    f16x8 a_[4];                                                                \
    _Pragma("unroll") for (int kq = 0; kq < 4; ++kq)                            \
        a_[kq] = *(const f16x8*)&hfrag[PRD][kq][col][quad*8];                   \
    f32x4 c_[3][2];                                                             \
    _Pragma("unroll") for (int g = 0; g < 3; ++g)                               \
    _Pragma("unroll") for (int hf = 0; hf < 2; ++hf){                           \
        f32x4 acc = {0.0f, 0.0f, 0.0f, 0.0f};                                   \
        _Pragma("unroll") for (int kq = 0; kq < 4; ++kq)                        \
            acc = __builtin_amdgcn_mfma_f32_16x16x32_f16(a_[kq], bfr[g][hf][kq], acc, 0,0,0); \
        c_[g][hf] = acc;                                                        \
    }                                                                           \
    _Pragma("unroll") for (int hf = 0; hf < 2; ++hf)                            \
    _Pragma("unroll") for (int rg = 0; rg < 4; ++rg){                           \
        float r_ = rcp_hw(1.0f + exp2_hw(-((float)XC[hf][rg][0] + c_[0][hf][rg] + bh[0][hf]))); \
        float z_ = rcp_hw(1.0f + exp2_hw(-((float)XC[hf][rg][1] + c_[1][hf][rg] + bh[1][hf]))); \
        float e_ = exp2_hw((float)XC[hf][rg][2] + r_*(c_[2][hf][rg] + bh[2][hf])); \
        float n_ = 1.0f - 2.0f*rcp_hw(e_ + 1.0f);                               \
        float h_ = n_ + z_*(hcur[hf][rg] - n_);                                 \
        hcur[hf][rg] = h_;                                                      \
        hfrag[PWR][w][quad*4 + rg][hf*16 + col] = (_Float16)h_;                 \
    }                                                                           \
    xp_d += DSTR;                                                               \
    BARRIER_NODRAIN();                                                          \
}while(0)

__global__ __launch_bounds__(256, 1) void gru_kernel(const _Float16* __restrict__ XP,
                                                     const _Float16* __restrict__ whh16,
                                                     const float* __restrict__ b_hh,
                                                     const float* __restrict__ w1, const float* __restrict__ b1,
                                                     const float* __restrict__ w2, const float* __restrict__ b2,
                                                     float* __restrict__ out){
    __shared__ _Float16 hfrag[2][4][16][40];  // 10 KB, MFMA-A fragment layout, dbuf, padded
    __shared__ float h_sh[16][132];           // final h for head (padded)

    const int tid  = threadIdx.x;
    const int lane = tid & 63, w = tid >> 6;      // 4 waves
    const int col  = lane & 15, quad = lane >> 4;
    const int row0 = blockIdx.x * 16;             // 16 seqs/block

    // zero h buffer (h0 = 0)
    for (int i = tid; i < 2*4*16*40; i += 256)
        ((_Float16*)hfrag)[i] = (_Float16)0.0f;

    // W_hh B-fragments: n = g*128 + w*32 + hf*16 + col, k = kq*32 + quad*8 + j
    f16x8 bfr[3][2][4];
    #pragma unroll
    for (int g = 0; g < 3; ++g)
    #pragma unroll
    for (int hf = 0; hf < 2; ++hf){
        int n = g*HH + w*32 + hf*16 + col;
        #pragma unroll
        for (int kq = 0; kq < 4; ++kq)
            bfr[g][hf][kq] = *(const f16x8*)&whh16[(size_t)n*HH + kq*32 + quad*8];
    }

    float bh[3][2];
    #pragma unroll
    for (int g = 0; g < 3; ++g)
    #pragma unroll
    for (int hf = 0; hf < 2; ++hf)
        bh[g][hf] = b_hh[g*HH + w*32 + hf*16 + col] * ((g < 2) ? L2E : L2E2);

    const size_t DSTR = (size_t)NN * G3;
    const _Float16* xp_d = XP + (size_t)(row0 + quad*4)*G3 + (w*32 + col);

    _Float16 xA[2][4][3], xB[2][4][3], xC[2][4][3];
    XLOAD(xA, xp_d);            // d = 0
    XLOAD(xB, xp_d + DSTR);     // d = 1

    float hcur[2][4] = {{0,0,0,0},{0,0,0,0}};
    __syncthreads();            // once: hfrag zero-init visible

    #pragma unroll 1
    for (int ch = 0; ch < 10; ++ch){
        const int pf = (ch < 9);          // last chunk: d+2 would be >= 60
        GRU_STEP(0, 1, xA, xC, 1);
        GRU_STEP(1, 0, xB, xA, 1);
        GRU_STEP(0, 1, xC, xB, 1);
        GRU_STEP(1, 0, xA, xC, 1);
        GRU_STEP(0, 1, xB, xA, pf);
        GRU_STEP(1, 0, xC, xB, pf);
    }

    #pragma unroll
    for (int hf = 0; hf < 2; ++hf)
    #pragma unroll
    for (int rg = 0; rg < 4; ++rg)
        h_sh[quad*4 + rg][w*32 + hf*16 + col] = hcur[hf][rg];
    __syncthreads();

    // ---- output head: 256 thr -> 4 rows in parallel, 4 passes ----
    {
        int c2 = tid & 63;
        int rb = tid >> 6;
        #pragma unroll
        for (int rr = 0; rr < 4; ++rr){
            int r = rb*4 + rr;
            float acc = 0.0f;
            #pragma unroll 8
            for (int k = 0; k < 128; ++k)
                acc = fmaf(h_sh[r][k], w1[k*64 + c2], acc);
            float hid = fmaxf(acc + b1[c2], 0.0f);
            float o = hid * w2[c2];
            #pragma unroll
            for (int off = 1; off < 64; off <<= 1) o += __shfl_xor(o, off, 64);
            if (c2 == 0) out[row0 + r] = o + b2[0];
        }
    }
}

extern "C" void kernel_launch(void* const* d_in, const int* in_sizes, int n_in,
                              void* d_out, int out_size, void* d_ws, size_t ws_size,
                              hipStream_t stream) {
    const float* x    = (const float*)d_in[0];
    const int*   mask = (const int*)d_in[1];
    const float* wq   = (const float*)d_in[2];
    const float* bq   = (const float*)d_in[3];
    const float* wk   = (const float*)d_in[4];
    const float* bk   = (const float*)d_in[5];
    const float* wv   = (const float*)d_in[6];
    const float* bv   = (const float*)d_in[7];
    const float* ln_g = (const float*)d_in[8];
    const float* ln_b = (const float*)d_in[9];
    const float* w_ih = (const float*)d_in[10];
    const float* w_hh = (const float*)d_in[11];
    const float* b_ih = (const float*)d_in[12];
    const float* b_hh = (const float*)d_in[13];
    const float* w1   = (const float*)d_in[14];
    const float* b1   = (const float*)d_in[15];
    const float* w2   = (const float*)d_in[16];
    const float* b2   = (const float*)d_in[17];

    float* ws = (float*)d_ws;
    // phase 1 (f32 index units):
    _Float16* Qh  = (_Float16*)ws;                    // f16 [0, 3,932,160)
    _Float16* Kh  = (_Float16*)(ws + 3932160);        // f16 [3,932,160, 7,864,320)
    // phase 2: XP aliases the dead Q/K region
    _Float16* XP  = (_Float16*)ws;                    // f16 [0, 23,592,960)
    float* market = ws + 23592960;                    //    15,360 f32
    _Float16* wf16 = (_Float16*)(ws + 23608320);      //    86,016 f16
    _Float16* wqk  = (_Float16*)(ws + 23651328);      //    20,480 f16
    _Float16* whh16= (_Float16*)(ws + 23666688);      //    49,152 f16
    // total ~94.8 MB

    prep_kernel<<<648, 256, 0, stream>>>(w_ih, wq, wk, w_hh, wf16, wqk, whh16);
    qk_kernel<<<1920, 256, 0, stream>>>(x, wqk, bq, bk, Qh, Kh);
    attn_kernel<<<240, 512, 0, stream>>>(Qh, Kh, mask, x, wv, bv, market);
    xproj_kernel<<<1920, 512, 0, stream>>>(x, market, ln_g, ln_b, wf16, b_ih, XP);
    gru_kernel<<<128, 256, 0, stream>>>(XP, whh16, b_hh, w1, b1, w2, b2, (float*)d_out);
}

// Round 8
// 343.446 us; speedup vs baseline: 1.0945x; 1.0098x over previous
//
#include <hip/hip_runtime.h>
#include <hip/hip_bf16.h>
#include <math.h>

#define BB 4
#define DD 60
#define SS 512
#define FF 158
#define CC 64
#define HH 128
#define FC 222      // F + C
#define G3 384      // 3H
#define NN 2048     // B*S
#define BDN 240     // B*D

#define L2E  1.44269504f
#define L2E2 2.88539008f
#define QSCALE 0.18033688f   // 0.125 * log2(e)

typedef _Float16 f16x8 __attribute__((ext_vector_type(8)));
typedef _Float16 f16x4 __attribute__((ext_vector_type(4)));
typedef float f32x4 __attribute__((ext_vector_type(4)));

__device__ __forceinline__ float exp2_hw(float x){ return __builtin_amdgcn_exp2f(x); }
__device__ __forceinline__ float rcp_hw(float x){ return __builtin_amdgcn_rcpf(x); }

// ---- prep: wf16 (384x224) xproj, wqk (128x160) qk, whh16 (384x128) gru ---------------
__global__ void prep_kernel(const float* __restrict__ w_ih,
                            const float* __restrict__ wq, const float* __restrict__ wk,
                            const float* __restrict__ w_hh,
                            _Float16* __restrict__ wf16, _Float16* __restrict__ wqk,
                            _Float16* __restrict__ whh16){
    int idx = blockIdx.x*256 + threadIdx.x;
    if (idx < 384*224){
        int n = idx / 224, k = idx % 224;
        float sc = (n < 256) ? L2E : L2E2;
        wf16[idx] = (k < FC) ? (_Float16)(w_ih[n*FC + k] * sc) : (_Float16)0.0f;
    } else if (idx < 384*224 + 128*160){
        int i2 = idx - 384*224;
        int n = i2 / 160, k = i2 % 160;
        float v = 0.0f;
        if (k < FF)
            v = (n < 64) ? wq[k*CC + n] : wk[k*CC + (n-64)];
        wqk[i2] = (_Float16)v;
    } else {
        int i3 = idx - (384*224 + 128*160);
        if (i3 < 384*128){
            int n = i3 / 128;
            float sc = (n < 256) ? L2E : L2E2;
            whh16[i3] = (_Float16)(w_hh[i3] * sc);
        }
    }
}

// ---------------- QK via f16 MFMA: 64 rows/block, 256 thr (4 waves) -------------------
__global__ __launch_bounds__(256) void qk_kernel(const float* __restrict__ x,
                           const _Float16* __restrict__ wqk,
                           const float* __restrict__ bq, const float* __restrict__ bk,
                           _Float16* __restrict__ Qh, _Float16* __restrict__ Kh){
    __shared__ _Float16 xa[5][64][40];   // fragment layout, 25.6 KB
    int tid  = threadIdx.x;
    int lane = tid & 63, wv = tid >> 6;
    int col  = lane & 15, quad = lane >> 4;
    int row0 = blockIdx.x * 64;

    f16x8 bfr[2][5];
    #pragma unroll
    for (int nt = 0; nt < 2; ++nt){
        int n = wv*32 + nt*16 + col;
        #pragma unroll
        for (int kq = 0; kq < 5; ++kq)
            bfr[nt][kq] = *(const f16x8*)&wqk[n*160 + kq*32 + quad*8];
    }

    if (tid < 128){
        int r = tid >> 1;
        xa[4][r][30 + (tid & 1)] = (_Float16)0.0f;
    }
    {
        const float4* xb4 = (const float4*)(x + (size_t)row0*FF);
        #pragma unroll
        for (int j = 0; j < 10; ++j){
            int i = tid + j*256;
            if (i < 2528){
                float4 v = xb4[i];
                int base = i*4;
                #pragma unroll
                for (int e = 0; e < 4; ++e){
                    int idx = base + e;
                    int r = idx / 158;
                    int k = idx - r*158;
                    xa[k >> 5][r][k & 31] = (_Float16)((&v.x)[e]);
                }
            }
        }
    }
    __syncthreads();

    float bias[2];
    #pragma unroll
    for (int nt = 0; nt < 2; ++nt){
        int n = wv*32 + nt*16 + col;
        bias[nt] = (n < 64) ? bq[n] : bk[n-64];
    }

    #pragma unroll 1
    for (int mt = 0; mt < 4; ++mt){
        f16x8 a[5];
        #pragma unroll
        for (int kq = 0; kq < 5; ++kq)
            a[kq] = *(const f16x8*)&xa[kq][mt*16 + col][quad*8];
        #pragma unroll
        for (int nt = 0; nt < 2; ++nt){
            f32x4 c = {0.0f, 0.0f, 0.0f, 0.0f};
            #pragma unroll
            for (int kq = 0; kq < 5; ++kq)
                c = __builtin_amdgcn_mfma_f32_16x16x32_f16(a[kq], bfr[nt][kq], c, 0, 0, 0);
            int n = wv*32 + nt*16 + col;
            #pragma unroll
            for (int reg = 0; reg < 4; ++reg){
                int row = row0 + mt*16 + quad*4 + reg;
                float val = c[reg] + bias[nt];
                if (n < 64) Qh[(size_t)row*CC + n]      = (_Float16)(val * QSCALE);
                else        Kh[(size_t)row*CC + (n-64)] = (_Float16)val;
            }
        }
    }
}

// ---------------- attention + fused market (V-free): one block per bd -----------------
__global__ __launch_bounds__(512) void attn_kernel(const _Float16* __restrict__ Qh,
                                                   const _Float16* __restrict__ Kh,
                                                   const int* __restrict__ mask,
                                                   const float* __restrict__ x,
                                                   const float* __restrict__ wv,
                                                   const float* __restrict__ bv,
                                                   float* __restrict__ market){
    __shared__ _Float16 kf[2][512][32];   // 64 KB
    __shared__ float w_sh[512];
    __shared__ float mk_lds[512];

    int tid  = threadIdx.x;
    int bd   = blockIdx.x;
    int lane = tid & 63, wvw = tid >> 6;
    int col  = lane & 15, quad = lane >> 4;

    const _Float16* qb = Qh + (size_t)(bd*SS)*CC;
    const _Float16* kb = Kh + (size_t)(bd*SS)*CC;

    {
        int t = tid;
        w_sh[t] = 0.0f;
        mk_lds[t] = (mask[bd*SS + t] != 0) ? 1.0f : 0.0f;
    }
    for (int i = tid; i < 4096; i += 512){
        int t = i >> 3, ch = i & 7;
        *(f16x8*)&kf[ch >> 2][t][(ch & 3)*8] = *(const f16x8*)&kb[t*CC + ch*8];
    }

    f16x8 a0[4], a1[4];
    #pragma unroll
    for (int af = 0; af < 4; ++af){
        int row = wvw*64 + af*16 + col;
        a0[af] = *(const f16x8*)&qb[row*CC + quad*8];
        a1[af] = *(const f16x8*)&qb[row*CC + 32 + quad*8];
    }
    __syncthreads();

    // ---- pass 0: row sums l ----
    float lacc[4][4] = {{0,0,0,0},{0,0,0,0},{0,0,0,0},{0,0,0,0}};
    #pragma unroll 2
    for (int kt = 0; kt < 32; ++kt){
        f16x8 b0 = *(const f16x8*)&kf[0][kt*16 + col][quad*8];
        f16x8 b1 = *(const f16x8*)&kf[1][kt*16 + col][quad*8];
        float mkv = mk_lds[kt*16 + col];
        #pragma unroll
        for (int af = 0; af < 4; ++af){
            f32x4 c = {0.0f, 0.0f, 0.0f, 0.0f};
            c = __builtin_amdgcn_mfma_f32_16x16x32_f16(a0[af], b0, c, 0, 0, 0);
            c = __builtin_amdgcn_mfma_f32_16x16x32_f16(a1[af], b1, c, 0, 0, 0);
            #pragma unroll
            for (int reg = 0; reg < 4; ++reg)
                lacc[af][reg] += exp2_hw(c[reg]) * mkv;
        }
    }
    float crv[4][4];
    #pragma unroll
    for (int af = 0; af < 4; ++af){
        #pragma unroll
        for (int reg = 0; reg < 4; ++reg){
            float l = lacc[af][reg];
            l += __shfl_xor(l, 1, 64);
            l += __shfl_xor(l, 2, 64);
            l += __shfl_xor(l, 4, 64);
            l += __shfl_xor(l, 8, 64);
            int row = wvw*64 + af*16 + quad*4 + reg;
            crv[af][reg] = mk_lds[row] * rcp_hw(l);
        }
    }

    // ---- pass 1: accumulate W columns ----
    #pragma unroll 2
    for (int kt = 0; kt < 32; ++kt){
        f16x8 b0 = *(const f16x8*)&kf[0][kt*16 + col][quad*8];
        f16x8 b1 = *(const f16x8*)&kf[1][kt*16 + col][quad*8];
        float s = 0.0f;
        #pragma unroll
        for (int af = 0; af < 4; ++af){
            f32x4 c = {0.0f, 0.0f, 0.0f, 0.0f};
            c = __builtin_amdgcn_mfma_f32_16x16x32_f16(a0[af], b0, c, 0, 0, 0);
            c = __builtin_amdgcn_mfma_f32_16x16x32_f16(a1[af], b1, c, 0, 0, 0);
            #pragma unroll
            for (int reg = 0; reg < 4; ++reg)
                s = fmaf(exp2_hw(c[reg]), crv[af][reg], s);
        }
        s += __shfl_xor(s, 16, 64);
        s += __shfl_xor(s, 32, 64);
        if (quad == 0)
            atomicAdd(&w_sh[kt*16 + col], s);
    }
    __syncthreads();

    // ---- fused market, V-free ----
    w_sh[tid] *= mk_lds[tid];
    __syncthreads();

    float* part = (float*)kf;
    {
        int tg = tid >> 8;
        int kk = tid & 255;
        float acc = 0.0f;
        if (kk < FF){
            const float* xb = x + ((size_t)bd*SS + tg*256)*FF + kk;
            #pragma unroll 8
            for (int t = 0; t < 256; ++t)
                acc = fmaf(w_sh[tg*256 + t], xb[(size_t)t*FF], acc);
        }
        part[tg*256 + kk] = acc;
    }
    __syncthreads();
    if (tid < 64){
        int c = tid;
        float m = 0.0f;
        for (int k = 0; k < FF; ++k){
            float y = part[k] + part[256 + k];
            m = fmaf(y, wv[k*CC + c], m);
        }
        float cnt = 0.0f, sw = 0.0f;
        #pragma unroll
        for (int j = 0; j < 8; ++j){
            cnt += mk_lds[c + 64*j];
            sw  += w_sh[c + 64*j];
        }
        #pragma unroll
        for (int o = 1; o < 64; o <<= 1){
            cnt += __shfl_xor(cnt, o, 64);
            sw  += __shfl_xor(sw,  o, 64);
        }
        market[bd*CC + c] = (m + sw*bv[c]) * rcp_hw(fmaxf(cnt, 1.0f));
    }
}

// ---------------- fused LN + x_proj f16 MFMA GEMM, XPP[d][blk][n][16] output ----------
__global__ __launch_bounds__(512, 2) void xproj_kernel(const float* __restrict__ x,
                             const float* __restrict__ market,
                             const float* __restrict__ ln_g, const float* __restrict__ ln_b,
                             const _Float16* __restrict__ wf16, const float* __restrict__ b_ih,
                             _Float16* __restrict__ XPP){
    __shared__ _Float16 aug[7][64][32];   // 28 KB
    int tid  = threadIdx.x;
    int lane = tid & 63, wv = tid >> 6;
    int col  = lane & 15, quad = lane >> 4;
    int row0 = blockIdx.x * 64;

    f16x8 bfr[3][7];
    #pragma unroll
    for (int nt = 0; nt < 3; ++nt){
        int n = wv*48 + nt*16 + col;
        #pragma unroll
        for (int kq = 0; kq < 7; ++kq)
            bfr[nt][kq] = *(const f16x8*)&wf16[n*224 + kq*32 + quad*8];
    }

    {
        int wrow = wv*8 + (lane >> 3);
        int g    = lane & 7;
        int row  = row0 + wrow;
        int d = row / NN, n = row % NN;
        int b = n >> 9, s = n & 511;
        const float* xr = &x[((size_t)((b*DD + d)*SS) + s)*FF];
        const float* mr = &market[(b*DD + d)*CC];
        float v[28];
        float sum = 0.0f, sq = 0.0f;
        #pragma unroll
        for (int j = 0; j < 28; ++j){
            int f = g + 8*j;
            float vv = 0.0f;
            if (f < FF) vv = xr[f];
            else if (f < FC) vv = mr[f - FF];
            v[j] = vv;
            sum += vv; sq += vv*vv;
        }
        sum += __shfl_xor(sum,1,64); sq += __shfl_xor(sq,1,64);
        sum += __shfl_xor(sum,2,64); sq += __shfl_xor(sq,2,64);
        sum += __shfl_xor(sum,4,64); sq += __shfl_xor(sq,4,64);
        float mu   = sum * (1.0f/222.0f);
        float var  = sq * (1.0f/222.0f) - mu*mu;
        float rstd = rsqrtf(var + 1e-5f);
        #pragma unroll
        for (int j = 0; j < 28; ++j){
            int f = g + 8*j;
            float val = (f < FC) ? ((v[j]-mu)*rstd*ln_g[f] + ln_b[f]) : 0.0f;
            aug[f>>5][wrow][f&31] = (_Float16)val;
        }
    }
    __syncthreads();

    float bias[3];
    #pragma unroll
    for (int nt = 0; nt < 3; ++nt){
        int n = wv*48 + nt*16 + col;
        bias[nt] = b_ih[n] * ((n < 256) ? L2E : L2E2);
    }
    const int d    = row0 / NN;
    const int blk0 = (row0 % NN) >> 4;
    // byte-addressed store base: XPP + ((d*128 + blk)*384 + nn)*16 elements
    #pragma unroll 1
    for (int mt = 0; mt < 4; ++mt){
        f16x8 a[7];
        #pragma unroll
        for (int kq = 0; kq < 7; ++kq)
            a[kq] = *(const f16x8*)&aug[kq][mt*16 + col][quad*8];
        _Float16* obase = XPP + ((size_t)(d*128 + blk0 + mt)*G3) * 16 + quad*4;
        #pragma unroll
        for (int nt = 0; nt < 3; ++nt){
            f32x4 c = {0.0f, 0.0f, 0.0f, 0.0f};
            #pragma unroll
            for (int kq = 0; kq < 7; ++kq)
                c = __builtin_amdgcn_mfma_f32_16x16x32_f16(a[kq], bfr[nt][kq], c, 0, 0, 0);
            int nn = wv*48 + nt*16 + col;
            f16x4 pk;
            pk[0] = (_Float16)(c[0] + bias[nt]);
            pk[1] = (_Float16)(c[1] + bias[nt]);
            pk[2] = (_Float16)(c[2] + bias[nt]);
            pk[3] = (_Float16)(c[3] + bias[nt]);
            *(f16x4*)(obase + (size_t)nn*16) = pk;
        }
    }
}

// ---------------- persistent GRU v5: 1 wave/SIMD, coalesced b64 XP reads --------------
// 128 blocks x 256 thr (4 waves). Wave w owns gate cols {g*128 + w*32 + [0,32)}:
// 24 MFMAs/step/wave, gates fully in registers. XPP[d][blk][n][16] layout: thread's
// 4 row-values at fixed n are one f16x4 (8 B) load; a wave covers a dense 512 B block
// per (g,hf) -> 6 coalesced b64 loads/thread/step (was 24 scalar f16).
#define XLOAD(dst, base_) do{                                                   \
    dst[0][0] = *(const f16x4*)((base_));                                       \
    dst[0][1] = *(const f16x4*)((base_) + 128*16);                              \
    dst[0][2] = *(const f16x4*)((base_) + 256*16);                              \
    dst[1][0] = *(const f16x4*)((base_) + 16*16);                               \
    dst[1][1] = *(const f16x4*)((base_) + 144*16);                              \
    dst[1][2] = *(const f16x4*)((base_) + 272*16);                              \
}while(0)

#define BARRIER_NODRAIN() asm volatile("s_waitcnt lgkmcnt(0)\ns_barrier" ::: "memory")

#define GRU_STEP(PRD, PWR, XC, XPF, DOPF) do{                                   \
    if (DOPF) { XLOAD(XPF, xp_d + 2*DSTR); }                                    \
    f16x8 a_[4];                                                                \
    _Pragma("unroll") for (int kq = 0; kq < 4; ++kq)                            \
        a_[kq] = *(const f16x8*)&hfrag[PRD][kq][col][quad*8];                   \
    f32x4 c_[3][2];                                                             \
    _Pragma("unroll") for (int g = 0; g < 3; ++g)                               \
    _Pragma("unroll") for (int hf = 0; hf < 2; ++hf){                           \
        f32x4 acc = {0.0f, 0.0f, 0.0f, 0.0f};                                   \
        _Pragma("unroll") for (int kq = 0; kq < 4; ++kq)                        \
            acc = __builtin_amdgcn_mfma_f32_16x16x32_f16(a_[kq], bfr[g][hf][kq], acc, 0,0,0); \
        c_[g][hf] = acc;                                                        \
    }                                                                           \
    _Pragma("unroll") for (int hf = 0; hf < 2; ++hf)                            \
    _Pragma("unroll") for (int rg = 0; rg < 4; ++rg){                           \
        float r_ = rcp_hw(1.0f + exp2_hw(-((float)XC[hf][0][rg] + c_[0][hf][rg] + bh[0][hf]))); \
        float z_ = rcp_hw(1.0f + exp2_hw(-((float)XC[hf][1][rg] + c_[1][hf][rg] + bh[1][hf]))); \
        float e_ = exp2_hw((float)XC[hf][2][rg] + r_*(c_[2][hf][rg] + bh[2][hf])); \
        float n_ = 1.0f - 2.0f*rcp_hw(e_ + 1.0f);                               \
        float h_ = n_ + z_*(hcur[hf][rg] - n_);                                 \
        hcur[hf][rg] = h_;                                                      \
        hfrag[PWR][w][quad*4 + rg][hf*16 + col] = (_Float16)h_;                 \
    }                                                                           \
    xp_d += DSTR;                                                               \
    BARRIER_NODRAIN();                                                          \
}while(0)

__global__ __launch_bounds__(256, 1) void gru_kernel(const _Float16* __restrict__ XPP,
                                                     const _Float16* __restrict__ whh16,
                                                     const float* __restrict__ b_hh,
                                                     const float* __restrict__ w1, const float* __restrict__ b1,
                                                     const float* __restrict__ w2, const float* __restrict__ b2,
                                                     float* __restrict__ out){
    __shared__ _Float16 hfrag[2][4][16][40];  // 10 KB, MFMA-A fragment layout, dbuf, padded
    __shared__ float h_sh[16][132];           // final h for head (padded)

    const int tid  = threadIdx.x;
    const int lane = tid & 63, w = tid >> 6;      // 4 waves
    const int col  = lane & 15, quad = lane >> 4;
    const int row0 = blockIdx.x * 16;             // 16 seqs/block; blk id = blockIdx.x

    for (int i = tid; i < 2*4*16*40; i += 256)
        ((_Float16*)hfrag)[i] = (_Float16)0.0f;

    // W_hh B-fragments: n = g*128 + w*32 + hf*16 + col
    f16x8 bfr[3][2][4];
    #pragma unroll
    for (int g = 0; g < 3; ++g)
    #pragma unroll
    for (int hf = 0; hf < 2; ++hf){
        int n = g*HH + w*32 + hf*16 + col;
        #pragma unroll
        for (int kq = 0; kq < 4; ++kq)
            bfr[g][hf][kq] = *(const f16x8*)&whh16[(size_t)n*HH + kq*32 + quad*8];
    }

    float bh[3][2];
    #pragma unroll
    for (int g = 0; g < 3; ++g)
    #pragma unroll
    for (int hf = 0; hf < 2; ++hf)
        bh[g][hf] = b_hh[g*HH + w*32 + hf*16 + col] * ((g < 2) ? L2E : L2E2);

    const size_t DSTR = (size_t)128 * G3 * 16;   // per-day stride in f16 units
    const _Float16* xp_d = XPP + ((size_t)blockIdx.x*G3 + (w*32 + col))*16 + quad*4;

    f16x4 xA[2][3], xB[2][3], xC[2][3];
    XLOAD(xA, xp_d);            // d = 0
    XLOAD(xB, xp_d + DSTR);     // d = 1

    float hcur[2][4] = {{0,0,0,0},{0,0,0,0}};
    __syncthreads();

    #pragma unroll 1
    for (int ch = 0; ch < 10; ++ch){
        const int pf = (ch < 9);
        GRU_STEP(0, 1, xA, xC, 1);
        GRU_STEP(1, 0, xB, xA, 1);
        GRU_STEP(0, 1, xC, xB, 1);
        GRU_STEP(1, 0, xA, xC, 1);
        GRU_STEP(0, 1, xB, xA, pf);
        GRU_STEP(1, 0, xC, xB, pf);
    }

    #pragma unroll
    for (int hf = 0; hf < 2; ++hf)
    #pragma unroll
    for (int rg = 0; rg < 4; ++rg)
        h_sh[quad*4 + rg][w*32 + hf*16 + col] = hcur[hf][rg];
    __syncthreads();

    // ---- output head ----
    {
        int c2 = tid & 63;
        int rb = tid >> 6;
        #pragma unroll
        for (int rr = 0; rr < 4; ++rr){
            int r = rb*4 + rr;
            float acc = 0.0f;
            #pragma unroll 8
            for (int k = 0; k < 128; ++k)
                acc = fmaf(h_sh[r][k], w1[k*64 + c2], acc);
            float hid = fmaxf(acc + b1[c2], 0.0f);
            float o = hid * w2[c2];
            #pragma unroll
            for (int off = 1; off < 64; off <<= 1) o += __shfl_xor(o, off, 64);
            if (c2 == 0) out[row0 + r] = o + b2[0];
        }
    }
}

extern "C" void kernel_launch(void* const* d_in, const int* in_sizes, int n_in,
                              void* d_out, int out_size, void* d_ws, size_t ws_size,
                              hipStream_t stream) {
    const float* x    = (const float*)d_in[0];
    const int*   mask = (const int*)d_in[1];
    const float* wq   = (const float*)d_in[2];
    const float* bq   = (const float*)d_in[3];
    const float* wk   = (const float*)d_in[4];
    const float* bk   = (const float*)d_in[5];
    const float* wv   = (const float*)d_in[6];
    const float* bv   = (const float*)d_in[7];
    const float* ln_g = (const float*)d_in[8];
    const float* ln_b = (const float*)d_in[9];
    const float* w_ih = (const float*)d_in[10];
    const float* w_hh = (const float*)d_in[11];
    const float* b_ih = (const float*)d_in[12];
    const float* b_hh = (const float*)d_in[13];
    const float* w1   = (const float*)d_in[14];
    const float* b1   = (const float*)d_in[15];
    const float* w2   = (const float*)d_in[16];
    const float* b2   = (const float*)d_in[17];

    float* ws = (float*)d_ws;
    // phase 1 (f32 index units):
    _Float16* Qh  = (_Float16*)ws;                    // f16 [0, 3,932,160)
    _Float16* Kh  = (_Float16*)(ws + 3932160);        // f16 [3,932,160, 7,864,320)
    // phase 2: XPP aliases the dead Q/K region; [60][128][384][16] f16 = 94.4 MB
    _Float16* XPP = (_Float16*)ws;
    float* market = ws + 23592960;                    //    15,360 f32
    _Float16* wf16 = (_Float16*)(ws + 23608320);      //    86,016 f16
    _Float16* wqk  = (_Float16*)(ws + 23651328);      //    20,480 f16
    _Float16* whh16= (_Float16*)(ws + 23666688);      //    49,152 f16
    // total ~94.8 MB

    prep_kernel<<<648, 256, 0, stream>>>(w_ih, wq, wk, w_hh, wf16, wqk, whh16);
    qk_kernel<<<1920, 256, 0, stream>>>(x, wqk, bq, bk, Qh, Kh);
    attn_kernel<<<240, 512, 0, stream>>>(Qh, Kh, mask, x, wv, bv, market);
    xproj_kernel<<<1920, 512, 0, stream>>>(x, market, ln_g, ln_b, wf16, b_ih, XPP);
    gru_kernel<<<128, 256, 0, stream>>>(XPP, whh16, b_hh, w1, b1, w2, b2, (float*)d_out);
}